// Round 23
// baseline (123.315 us; speedup 1.0000x reference)
//
#include <hip/hip_runtime.h>
#include <hip/hip_bf16.h>

// Sggnn_gcn — fused 2x(Linear512+BN+LReLU) + Wc projection, then GCN on 2-wide
// features. Restructuring: (w_norm^T @ t) @ Wc^T == w_norm^T @ (t @ Wc^T).
// v23: barrier-minimal single-buffer fused_mlp. A-tile reads and T1 writes are
// temporally disjoint -> share ONE 64 KB fragment-major LDS buffer:
//   stage whole A tile -> B1 -> phase-1 K-loop (ZERO barriers, contiguous
//   reads, dual-W prefetch) -> B2 -> epi-1 writes T1 fragment-major over the
//   same buffer -> B3 -> phase-2 (barrier-free, contiguous, XOR swizzle GONE)
//   -> B4 -> Ured reduce. 4-5 barriers/tile vs v22's 11. Staging's serial
//   ~1400cyc is hidden by the co-resident 2nd block.

typedef __hip_bfloat16 bf16_t;
typedef __bf16 bf16x8 __attribute__((ext_vector_type(8)));
typedef __bf16 bf16x4 __attribute__((ext_vector_type(4)));
typedef float f32x4 __attribute__((ext_vector_type(4)));

#define KDIM 512
#define BM 64

__device__ __forceinline__ float ldsel(const void* p, int i, int isbf) {
    return isbf ? __bfloat162float(((const bf16_t*)p)[i]) : ((const float*)p)[i];
}

// dtype sniff from the first 64 u16 words (bf16 -> ~64 hits; f32 -> ~34)
__device__ __forceinline__ int detect_isbf(const void* p) {
    const unsigned short* u = (const unsigned short*)p;
    int cnt = 0;
    #pragma unroll
    for (int i = 0; i < 64; ++i) {
        const int e = (u[i] >> 7) & 0xFF;
        cnt += (e >= 118 && e <= 129) ? 1 : 0;
    }
    return cnt >= 48;
}

// ---- merged prep: blocks 0..127 = wconv, 128..255 = rowsum, 256 = params+flag ----
__global__ void prep_kernel(const void* __restrict__ d, const void* __restrict__ w,
                            const void* __restrict__ W1, const void* __restrict__ W2,
                            const void* g1, const void* b1, const void* m1,
                            const void* v1, const void* be1,
                            const void* g2, const void* b2, const void* m2,
                            const void* v2, const void* be2,
                            const void* Wc, const void* bc,
                            float* __restrict__ dinv,
                            bf16_t* __restrict__ W1pk, bf16_t* __restrict__ W2pk,
                            float* sc1, float* sh1, float* sc2, float* sh2,
                            float* wcf, float* bcf, int* __restrict__ flag) {
    const int blk = blockIdx.x;
    const int tid = threadIdx.x;
    if (blk < 128) {
        // W1,W2 -> bf16 FRAGMENT-MAJOR
        const int isbf = detect_isbf(W1);
        const int t = blk * 256 + tid;          // 0..32767
        const int lane = t & 63;
        const int kt = (t >> 6) & 15;
        const int c16 = t >> 10;
        const int src = (c16 * 16 + (lane & 15)) * 512 + kt * 32 + (lane >> 4) * 8;
        bf16x8 v1v, v2v;
        #pragma unroll
        for (int e = 0; e < 8; ++e) {
            v1v[e] = (__bf16)ldsel(W1, src + e, isbf);
            v2v[e] = (__bf16)ldsel(W2, src + e, isbf);
        }
        *reinterpret_cast<bf16x8*>(W1pk + (size_t)t * 8) = v1v;
        *reinterpret_cast<bf16x8*>(W2pk + (size_t)t * 8) = v2v;
    } else if (blk < 256) {
        // rowsum of adj = w + I -> d_inv_sqrt; one row per wave
        const int isbf = detect_isbf(w);
        const int wave = tid >> 6, lane = tid & 63;
        const int row = (blk - 128) * 4 + wave;
        float s = 0.f;
        for (int j = lane; j < 512; j += 64) s += ldsel(w, row * 512 + j, isbf);
        #pragma unroll
        for (int off = 32; off; off >>= 1) s += __shfl_down(s, off, 64);
        if (lane == 0) dinv[row] = 1.0f / sqrtf(s + 1.0f);
    } else {
        // BN fold + Wc/bc canonicalize + global dtype flag (from d)
        const int isbf = detect_isbf(g1);
        for (int i = tid; i < 512; i += 256) {
            float s1 = ldsel(g1, i, isbf) / sqrtf(ldsel(v1, i, isbf) + 1e-5f);
            sc1[i] = s1;
            sh1[i] = (ldsel(b1, i, isbf) - ldsel(m1, i, isbf)) * s1 + ldsel(be1, i, isbf);
            float s2 = ldsel(g2, i, isbf) / sqrtf(ldsel(v2, i, isbf) + 1e-5f);
            sc2[i] = s2;
            sh2[i] = (ldsel(b2, i, isbf) - ldsel(m2, i, isbf)) * s2 + ldsel(be2, i, isbf);
            wcf[i] = ldsel(Wc, i, isbf);
            wcf[512 + i] = ldsel(Wc, 512 + i, isbf);
        }
        if (tid < 2) bcf[tid] = ldsel(bc, tid, isbf);
        if (tid == 0) *flag = detect_isbf(d);
    }
}

#define FJSTRIDE 16384
#define FKSTRIDE 1024

#define LOADW4(dst, base, kt)                                                  \
    _Pragma("unroll")                                                          \
    for (int j_ = 0; j_ < 4; ++j_)                                             \
        dst[j_] = *reinterpret_cast<const bf16x8*>((base) + j_ * FJSTRIDE + (kt) * FKSTRIDE);

// contiguous fragment reads (lane*16) from Sfm + 16 MFMA for k-tile kt
#define COMPUTES(kt, bWs)                                                      \
    {                                                                          \
        __builtin_amdgcn_s_setprio(1);                                         \
        _Pragma("unroll")                                                      \
        for (int i_ = 0; i_ < 4; ++i_) {                                       \
            bf16x8 af_ = *reinterpret_cast<const bf16x8*>(                     \
                (const char*)Sfm + (kt) * 4096 + i_ * 1024 + lane * 16);       \
            _Pragma("unroll")                                                  \
            for (int j_ = 0; j_ < 4; ++j_)                                     \
                acc[j_][i_] = __builtin_amdgcn_mfma_f32_16x16x32_bf16(bWs[j_], af_, acc[j_][i_], 0, 0, 0); \
        }                                                                      \
        __builtin_amdgcn_s_setprio(0);                                         \
    }

// ---- fused MLP: 8 waves, BM=64, 2 blocks/CU; single shared fragment buffer ----
__launch_bounds__(512, 4)
__global__ void fused_mlp(const void* __restrict__ A,      // d: f32 or bf16, 65536x512
                          const bf16_t* __restrict__ W1pk, // fragment-major bf16
                          const bf16_t* __restrict__ W2pk,
                          const float* __restrict__ sc1, const float* __restrict__ sh1,
                          const float* __restrict__ sc2, const float* __restrict__ sh2,
                          const float* __restrict__ wcf,   // 1024 f32
                          const int* __restrict__ flagp,
                          float* __restrict__ U)           // 65536 x 2
{
    __shared__ __align__(16) bf16_t Sfm[BM * KDIM];   // 64 KB: A tile, then T1
    __shared__ float Ured[8][BM][2];                  // 4 KB

    const int isbf = *flagp;                    // wave-uniform scalar load
    const int tid = threadIdx.x;
    const int wave = tid >> 6, lane = tid & 63;
    const int rl = lane & 15, hi = lane >> 4;
    const int wc = wave;                        // wave owns cols wc*64..+64
    const int tile = blockIdx.x;                // 0..1023; rows tile*64..+64

    const char* w1base = (const char*)W1pk + ((size_t)(wc * 4) * 16 * 64 + lane) * 16;
    const char* w2base = (const char*)W2pk + ((size_t)(wc * 4) * 16 * 64 + lane) * 16;

    f32x4 acc[4][4] = {};

    // ===== stage the WHOLE A tile fragment-major (convert once) =====
    {
        const int srow = tid >> 3;              // 0..63
        const int sk8b = tid & 7;               // 0..7
        #pragma unroll 2
        for (int rr = 0; rr < 8; ++rr) {
            const int k8 = sk8b + rr * 8;       // 8-elem chunk index 0..63
            const size_t ge = ((size_t)(tile * BM) + srow) * KDIM + (size_t)k8 * 8;
            bf16x8 v_;
            if (isbf) {
                v_ = *reinterpret_cast<const bf16x8*>((const bf16_t*)A + ge);
            } else {
                const f32x4* p_ = (const f32x4*)((const float*)A + ge);
                const f32x4 a0 = p_[0], a1 = p_[1];
                v_[0] = (__bf16)a0.x; v_[1] = (__bf16)a0.y;
                v_[2] = (__bf16)a0.z; v_[3] = (__bf16)a0.w;
                v_[4] = (__bf16)a1.x; v_[5] = (__bf16)a1.y;
                v_[6] = (__bf16)a1.z; v_[7] = (__bf16)a1.w;
            }
            const int soff = (k8 >> 2) * 4096 + (srow >> 4) * 1024
                             + ((k8 & 3) * 16 + (srow & 15)) * 16;
            *reinterpret_cast<bf16x8*>((char*)Sfm + soff) = v_;
        }
    }
    __syncthreads();   // B1: A tile staged

    // ===== phase 1: T1 = lrelu(bn1(A @ W1^T)) — ZERO barriers =====
    {
        bf16x8 bW0[4], bW1[4];
        LOADW4(bW0, w1base, 0);
        #pragma unroll 1
        for (int kt = 0; kt < 16; kt += 2) {
            LOADW4(bW1, w1base, kt + 1);
            COMPUTES(kt, bW0);
            if (kt + 2 < 16) LOADW4(bW0, w1base, kt + 2);
            COMPUTES(kt + 1, bW1);
        }
    }
    __syncthreads();   // B2: all A reads done; safe to overwrite Sfm

    // ===== epilogue 1: BN + LReLU -> T1 fragment-major into Sfm =====
    #pragma unroll
    for (int j = 0; j < 4; ++j) {
        const int col0 = wc * 64 + j * 16 + hi * 4;
        const f32x4 s4 = *reinterpret_cast<const f32x4*>(&sc1[col0]);
        const f32x4 h4 = *reinterpret_cast<const f32x4*>(&sh1[col0]);
        const int ktt = col0 >> 5;
        const int hh = (col0 & 31) >> 3;
        const int eo = (hi & 1) * 8;
        #pragma unroll
        for (int i = 0; i < 4; ++i) {
            bf16x4 pk;
            #pragma unroll
            for (int r = 0; r < 4; ++r) {
                float y = acc[j][i][r] * s4[r] + h4[r];
                y = y > 0.f ? y : 0.1f * y;
                pk[r] = (__bf16)y;
            }
            *reinterpret_cast<bf16x4*>((char*)Sfm + ktt * 4096 + i * 1024
                                       + (hh * 16 + rl) * 16 + eo) = pk;
        }
    }
    __syncthreads();   // B3: T1 visible

    // ===== phase 2: U = proj(lrelu(bn2(T1 @ W2^T))) — barrier-free =====
    #pragma unroll
    for (int j = 0; j < 4; ++j)
        #pragma unroll
        for (int i = 0; i < 4; ++i)
            acc[j][i] = f32x4{0.f, 0.f, 0.f, 0.f};

    {
        bf16x8 bW0[4], bW1[4];
        LOADW4(bW0, w2base, 0);
        #pragma unroll 1
        for (int kt = 0; kt < 16; kt += 2) {
            LOADW4(bW1, w2base, kt + 1);
            COMPUTES(kt, bW0);
            if (kt + 2 < 16) LOADW4(bW0, w2base, kt + 2);
            COMPUTES(kt + 1, bW1);
        }
    }

    // ===== epilogue 2: BN + LReLU + 512->2 projection =====
    float p0[4] = {0.f, 0.f, 0.f, 0.f}, p1[4] = {0.f, 0.f, 0.f, 0.f};
    #pragma unroll
    for (int j = 0; j < 4; ++j) {
        const int col0 = wc * 64 + j * 16 + hi * 4;
        const f32x4 s4 = *reinterpret_cast<const f32x4*>(&sc2[col0]);
        const f32x4 h4 = *reinterpret_cast<const f32x4*>(&sh2[col0]);
        const f32x4 w0 = *reinterpret_cast<const f32x4*>(&wcf[col0]);
        const f32x4 w1 = *reinterpret_cast<const f32x4*>(&wcf[512 + col0]);
        #pragma unroll
        for (int i = 0; i < 4; ++i)
            #pragma unroll
            for (int r = 0; r < 4; ++r) {
                float y = acc[j][i][r] * s4[r] + h4[r];
                y = y > 0.f ? y : 0.1f * y;
                p0[i] += y * w0[r];
                p1[i] += y * w1[r];
            }
    }
    #pragma unroll
    for (int i = 0; i < 4; ++i) {
        float a = p0[i], b = p1[i];
        a += __shfl_xor(a, 16, 64);  b += __shfl_xor(b, 16, 64);
        a += __shfl_xor(a, 32, 64);  b += __shfl_xor(b, 32, 64);
        if (hi == 0) {
            Ured[wc][i * 16 + rl][0] = a;
            Ured[wc][i * 16 + rl][1] = b;
        }
    }
    __syncthreads();   // B4: Ured ready
    if (tid < BM * 2) {
        const int row = tid >> 1, c = tid & 1;
        float s = 0.f;
        #pragma unroll
        for (int q = 0; q < 8; ++q) s += Ured[q][row][c];
        U[(size_t)(tile * BM + row) * 2 + c] = s;
    }
}

// ---- GCN on 2-wide features, dinv scaling applied inline on raw w ----
// out[b,n,c] = dinv[n] * sum_m (w[n,m] + (m==n)) * dinv[m] * U[b*512+m, c] + bc[c]
__global__ void gcn_kernel(const void* __restrict__ w, const float* __restrict__ dinv,
                           const float* __restrict__ U, const float* __restrict__ bcf,
                           const int* __restrict__ flagp, void* __restrict__ out) {
    const int isbf = *flagp;                  // wave-uniform scalar load
    const int wave = threadIdx.x >> 6, lane = threadIdx.x & 63;
    const int task = blockIdx.x * 4 + wave;   // (b, n)
    const int b = task >> 9, n = task & 511;
    const float* ub = U + b * 1024;
    float a0 = 0.f, a1 = 0.f;
    for (int m = lane; m < 512; m += 64) {
        float wv = ldsel(w, n * 512 + m, isbf) + (m == n ? 1.0f : 0.0f);
        const float t = wv * dinv[m];
        a0 += t * ub[m * 2];
        a1 += t * ub[m * 2 + 1];
    }
    #pragma unroll
    for (int off = 32; off; off >>= 1) {
        a0 += __shfl_down(a0, off, 64);
        a1 += __shfl_down(a1, off, 64);
    }
    if (lane == 0) {
        const float dn = dinv[n];
        const float r0 = a0 * dn + bcf[0];
        const float r1 = a1 * dn + bcf[1];
        if (isbf) {
            ((bf16_t*)out)[task * 2]     = __float2bfloat16(r0);
            ((bf16_t*)out)[task * 2 + 1] = __float2bfloat16(r1);
        } else {
            ((float*)out)[task * 2]     = r0;
            ((float*)out)[task * 2 + 1] = r1;
        }
    }
}

extern "C" void kernel_launch(void* const* d_in, const int* in_sizes, int n_in,
                              void* d_out, int out_size, void* d_ws, size_t ws_size,
                              hipStream_t stream) {
    const void* d   = d_in[0];
    const void* w   = d_in[1];
    const void* W1  = d_in[2];
    const void* b1  = d_in[3];
    const void* g1  = d_in[4];
    const void* be1 = d_in[5];
    const void* m1  = d_in[6];
    const void* v1  = d_in[7];
    const void* W2  = d_in[8];
    const void* b2  = d_in[9];
    const void* g2  = d_in[10];
    const void* be2 = d_in[11];
    const void* m2  = d_in[12];
    const void* v2  = d_in[13];
    const void* Wc  = d_in[14];
    const void* bc  = d_in[15];

    // workspace layout: ~1.6 MB total
    char* ws = (char*)d_ws;
    bf16_t* W1pk = (bf16_t*)ws;                        // 512 KB (fragment-major)
    bf16_t* W2pk = (bf16_t*)(ws + 0x080000);           // 512 KB
    float*  sc1  = (float*)(ws + 0x100000);
    float*  sh1  = sc1 + 512;
    float*  sc2  = sh1 + 512;
    float*  sh2  = sc2 + 512;
    float*  dinv = sh2 + 512;
    float*  wcf  = (float*)(ws + 0x104000);            // 4 KB
    float*  bcf  = (float*)(ws + 0x105000);
    int*    flag = (int*)(ws + 0x105100);
    float*  U    = (float*)(ws + 0x108000);            // 512 KB

    const int M = 128 * 512;   // 65536 rows

    prep_kernel<<<257, 256, 0, stream>>>(d, w, W1, W2, g1, b1, m1, v1, be1,
                                         g2, b2, m2, v2, be2, Wc, bc,
                                         dinv, W1pk, W2pk, sc1, sh1, sc2, sh2,
                                         wcf, bcf, flag);

    fused_mlp<<<M / BM, 512, 0, stream>>>(d, W1pk, W2pk,
                                          sc1, sh1, sc2, sh2, wcf, flag, U);

    gcn_kernel<<<M / 4, 256, 0, stream>>>(w, dinv, U, bcf, flag, d_out);
}

// Round 24
// 120.343 us; speedup vs baseline: 1.0247x; 1.0247x over previous
//
#include <hip/hip_runtime.h>
#include <hip/hip_bf16.h>

// Sggnn_gcn — fused 2x(Linear512+BN+LReLU) + Wc projection, then GCN on 2-wide
// features. Restructuring: (w_norm^T @ t) @ Wc^T == w_norm^T @ (t @ Wc^T).
// v24 = measured-best recombination: v19's exact fused_mlp (fastest measured,
// 101.5us: single-W set, 8-barrier double-buffered bf16 fragment-major A
// staging, no setprio) inside v21's 3-launch shell (merged prep computes the
// dtype flag once; gcn applies dinv scaling inline on raw w).

typedef __hip_bfloat16 bf16_t;
typedef __bf16 bf16x8 __attribute__((ext_vector_type(8)));
typedef __bf16 bf16x4 __attribute__((ext_vector_type(4)));
typedef float f32x4 __attribute__((ext_vector_type(4)));

#define KDIM 512
#define BM 64

__device__ __forceinline__ float ldsel(const void* p, int i, int isbf) {
    return isbf ? __bfloat162float(((const bf16_t*)p)[i]) : ((const float*)p)[i];
}

// dtype sniff from the first 64 u16 words (bf16 -> ~64 hits; f32 -> ~34)
__device__ __forceinline__ int detect_isbf(const void* p) {
    const unsigned short* u = (const unsigned short*)p;
    int cnt = 0;
    #pragma unroll
    for (int i = 0; i < 64; ++i) {
        const int e = (u[i] >> 7) & 0xFF;
        cnt += (e >= 118 && e <= 129) ? 1 : 0;
    }
    return cnt >= 48;
}

// ---- merged prep: blocks 0..127 = wconv, 128..255 = rowsum, 256 = params+flag ----
__global__ void prep_kernel(const void* __restrict__ d, const void* __restrict__ w,
                            const void* __restrict__ W1, const void* __restrict__ W2,
                            const void* g1, const void* b1, const void* m1,
                            const void* v1, const void* be1,
                            const void* g2, const void* b2, const void* m2,
                            const void* v2, const void* be2,
                            const void* Wc, const void* bc,
                            float* __restrict__ dinv,
                            bf16_t* __restrict__ W1pk, bf16_t* __restrict__ W2pk,
                            float* sc1, float* sh1, float* sc2, float* sh2,
                            float* wcf, float* bcf, int* __restrict__ flag) {
    const int blk = blockIdx.x;
    const int tid = threadIdx.x;
    if (blk < 128) {
        // W1,W2 -> bf16 FRAGMENT-MAJOR
        const int isbf = detect_isbf(W1);
        const int t = blk * 256 + tid;          // 0..32767
        const int lane = t & 63;
        const int kt = (t >> 6) & 15;
        const int c16 = t >> 10;
        const int src = (c16 * 16 + (lane & 15)) * 512 + kt * 32 + (lane >> 4) * 8;
        bf16x8 v1v, v2v;
        #pragma unroll
        for (int e = 0; e < 8; ++e) {
            v1v[e] = (__bf16)ldsel(W1, src + e, isbf);
            v2v[e] = (__bf16)ldsel(W2, src + e, isbf);
        }
        *reinterpret_cast<bf16x8*>(W1pk + (size_t)t * 8) = v1v;
        *reinterpret_cast<bf16x8*>(W2pk + (size_t)t * 8) = v2v;
    } else if (blk < 256) {
        // rowsum of adj = w + I -> d_inv_sqrt; one row per wave
        const int isbf = detect_isbf(w);
        const int wave = tid >> 6, lane = tid & 63;
        const int row = (blk - 128) * 4 + wave;
        float s = 0.f;
        for (int j = lane; j < 512; j += 64) s += ldsel(w, row * 512 + j, isbf);
        #pragma unroll
        for (int off = 32; off; off >>= 1) s += __shfl_down(s, off, 64);
        if (lane == 0) dinv[row] = 1.0f / sqrtf(s + 1.0f);
    } else {
        // BN fold + Wc/bc canonicalize + global dtype flag (from d)
        const int isbf = detect_isbf(g1);
        for (int i = tid; i < 512; i += 256) {
            float s1 = ldsel(g1, i, isbf) / sqrtf(ldsel(v1, i, isbf) + 1e-5f);
            sc1[i] = s1;
            sh1[i] = (ldsel(b1, i, isbf) - ldsel(m1, i, isbf)) * s1 + ldsel(be1, i, isbf);
            float s2 = ldsel(g2, i, isbf) / sqrtf(ldsel(v2, i, isbf) + 1e-5f);
            sc2[i] = s2;
            sh2[i] = (ldsel(b2, i, isbf) - ldsel(m2, i, isbf)) * s2 + ldsel(be2, i, isbf);
            wcf[i] = ldsel(Wc, i, isbf);
            wcf[512 + i] = ldsel(Wc, 512 + i, isbf);
        }
        if (tid < 2) bcf[tid] = ldsel(bc, tid, isbf);
        if (tid == 0) *flag = detect_isbf(d);
    }
}

#define FJSTRIDE 16384
#define FKSTRIDE 1024

#define LOADW4(dst, base, kt)                                                  \
    _Pragma("unroll")                                                          \
    for (int j_ = 0; j_ < 4; ++j_)                                             \
        dst[j_] = *reinterpret_cast<const bf16x8*>((base) + j_ * FJSTRIDE + (kt) * FKSTRIDE);

// issue staging loads for round r (BK=64) into the single staging set
#define SLOAD(r)                                                               \
    {                                                                          \
        if (isbf) {                                                            \
            sb = *reinterpret_cast<const bf16x8*>((const bf16_t*)A + sgb + (size_t)(r) * 64); \
        } else {                                                               \
            const f32x4* p_ = (const f32x4*)((const float*)A + sgb + (size_t)(r) * 64); \
            sf[0] = p_[0]; sf[1] = p_[1];                                      \
        }                                                                      \
    }

// convert + ds_write the staging set into Asg[buf] (fragment-major, 8 KB/round)
#define SWRITE(buf)                                                            \
    {                                                                          \
        bf16x8 v_;                                                             \
        if (isbf) { v_ = sb; }                                                 \
        else {                                                                 \
            v_[0] = (__bf16)sf[0].x; v_[1] = (__bf16)sf[0].y;                  \
            v_[2] = (__bf16)sf[0].z; v_[3] = (__bf16)sf[0].w;                  \
            v_[4] = (__bf16)sf[1].x; v_[5] = (__bf16)sf[1].y;                  \
            v_[6] = (__bf16)sf[1].z; v_[7] = (__bf16)sf[1].w;                  \
        }                                                                      \
        *reinterpret_cast<bf16x8*>((char*)Asg + (buf) * 8192 + sldsoff) = v_;  \
    }

// fragment reads (contiguous lane*16) + 16 MFMA for k-tile (buf, q)
#define COMPUTEQ(buf, q, bWs)                                                  \
    _Pragma("unroll")                                                          \
    for (int i_ = 0; i_ < 4; ++i_) {                                           \
        bf16x8 af_ = *reinterpret_cast<const bf16x8*>(                         \
            (const char*)Asg + (buf) * 8192 + (q) * 4096 + i_ * 1024 + lane * 16); \
        _Pragma("unroll")                                                      \
        for (int j_ = 0; j_ < 4; ++j_)                                         \
            acc[j_][i_] = __builtin_amdgcn_mfma_f32_16x16x32_bf16(bWs[j_], af_, acc[j_][i_], 0, 0, 0); \
    }

// T1s frag read + 4x4 MFMA (phase 2)
#define COMPT1(kt, bWs)                                                        \
    _Pragma("unroll")                                                          \
    for (int i_ = 0; i_ < 4; ++i_) {                                           \
        const int row_ = i_ * 16 + rl;                                         \
        int off_ = (row_ << 10) + (kt) * 64 + hi * 16;                         \
        off_ ^= (row_ & 7) << 4;                                               \
        bf16x8 af_ = *reinterpret_cast<const bf16x8*>((const char*)T1s + off_);\
        _Pragma("unroll")                                                      \
        for (int j_ = 0; j_ < 4; ++j_)                                         \
            acc[j_][i_] = __builtin_amdgcn_mfma_f32_16x16x32_bf16(bWs[j_], af_, acc[j_][i_], 0, 0, 0); \
    }

// ---- fused MLP: 8 waves, BM=64, 2 blocks/CU (v19 verbatim) ----
__launch_bounds__(512, 4)
__global__ void fused_mlp(const void* __restrict__ A,      // d: f32 or bf16, 65536x512
                          const bf16_t* __restrict__ W1pk, // fragment-major bf16
                          const bf16_t* __restrict__ W2pk,
                          const float* __restrict__ sc1, const float* __restrict__ sh1,
                          const float* __restrict__ sc2, const float* __restrict__ sh2,
                          const float* __restrict__ wcf,   // 1024 f32
                          const int* __restrict__ flagp,
                          float* __restrict__ U)           // 65536 x 2
{
    __shared__ __align__(16) bf16_t T1s[BM * KDIM];   // 64 KB row-major swizzled
    __shared__ __align__(16) bf16_t Asg[2][BM * 64];  // 2 x 8 KB fragment-major
    float* UredF = (float*)Asg;                       // 4 KB overlay after phase 1

    const int isbf = *flagp;                    // wave-uniform scalar load
    const int tid = threadIdx.x;
    const int wave = tid >> 6, lane = tid & 63;
    const int rl = lane & 15, hi = lane >> 4;
    const int wc = wave;                        // wave owns cols wc*64..+64
    const int tile = blockIdx.x;                // 0..1023; rows tile*64..+64

    const char* w1base = (const char*)W1pk + ((size_t)(wc * 4) * 16 * 64 + lane) * 16;
    const char* w2base = (const char*)W2pk + ((size_t)(wc * 4) * 16 * 64 + lane) * 16;

    // staging: thread covers row srow, 8-elem chunk sk8; fragment-major LDS dest
    const int srow = tid >> 3;                  // 0..63
    const int sk8 = tid & 7;                    // 0..7
    const int sq = sk8 >> 2, sc8 = sk8 & 3;
    const size_t sgb = ((size_t)(tile * BM) + srow) * KDIM + sk8 * 8;   // element idx
    const int sldsoff = (sq * 256 + (srow >> 4) * 64 + (srow & 15) + sc8 * 16) * 16;

    f32x4 acc[4][4] = {};
    f32x4 sf[2];
    bf16x8 sb;

    // ================= phase 1: T1 = lrelu(bn1(A @ W1^T)) =================
    SLOAD(0);
    SWRITE(0);          // round 0 -> buf0 (vmcnt wait via dependency)
    SLOAD(1);           // round 1 in flight, written end of round 0
    __syncthreads();    // buf0 visible

    {
        bf16x8 bW[4];
        #pragma unroll 1
        for (int r = 0; r < 8; ++r) {
            LOADW4(bW, w1base, 2 * r);
            COMPUTEQ(r & 1, 0, bW);
            LOADW4(bW, w1base, 2 * r + 1);
            COMPUTEQ(r & 1, 1, bW);
            if (r + 1 < 8) SWRITE((r + 1) & 1);   // data loaded one round ago
            if (r + 2 < 8) SLOAD(r + 2);          // full-round cover
            __syncthreads();
        }
    }

    // epilogue 1: BN + LReLU -> swizzled T1s
    #pragma unroll
    for (int j = 0; j < 4; ++j) {
        const int col0 = wc * 64 + j * 16 + hi * 4;
        const f32x4 s4 = *reinterpret_cast<const f32x4*>(&sc1[col0]);
        const f32x4 h4 = *reinterpret_cast<const f32x4*>(&sh1[col0]);
        #pragma unroll
        for (int i = 0; i < 4; ++i) {
            const int row = i * 16 + rl;
            int off = (row << 10) + (col0 << 1);
            off ^= (row & 7) << 4;
            bf16x4 pk;
            #pragma unroll
            for (int r = 0; r < 4; ++r) {
                float y = acc[j][i][r] * s4[r] + h4[r];
                y = y > 0.f ? y : 0.1f * y;
                pk[r] = (__bf16)y;
            }
            *reinterpret_cast<bf16x4*>((char*)T1s + off) = pk;
        }
    }
    __syncthreads();   // T1s visible to all waves

    // ================= phase 2: U = proj(lrelu(bn2(T1 @ W2^T))) — barrier-free ==
    #pragma unroll
    for (int j = 0; j < 4; ++j)
        #pragma unroll
        for (int i = 0; i < 4; ++i)
            acc[j][i] = f32x4{0.f, 0.f, 0.f, 0.f};

    {
        bf16x8 bW0[4], bW1[4];
        LOADW4(bW0, w2base, 0);
        #pragma unroll 1
        for (int kt = 0; kt < 16; kt += 2) {
            LOADW4(bW1, w2base, kt + 1);
            COMPT1(kt, bW0);
            if (kt + 2 < 16) LOADW4(bW0, w2base, kt + 2);
            COMPT1(kt + 1, bW1);
        }
    }

    // epilogue 2: BN + LReLU + 512->2 projection
    float p0[4] = {0.f, 0.f, 0.f, 0.f}, p1[4] = {0.f, 0.f, 0.f, 0.f};
    #pragma unroll
    for (int j = 0; j < 4; ++j) {
        const int col0 = wc * 64 + j * 16 + hi * 4;
        const f32x4 s4 = *reinterpret_cast<const f32x4*>(&sc2[col0]);
        const f32x4 h4 = *reinterpret_cast<const f32x4*>(&sh2[col0]);
        const f32x4 w0 = *reinterpret_cast<const f32x4*>(&wcf[col0]);
        const f32x4 w1 = *reinterpret_cast<const f32x4*>(&wcf[512 + col0]);
        #pragma unroll
        for (int i = 0; i < 4; ++i)
            #pragma unroll
            for (int r = 0; r < 4; ++r) {
                float y = acc[j][i][r] * s4[r] + h4[r];
                y = y > 0.f ? y : 0.1f * y;
                p0[i] += y * w0[r];
                p1[i] += y * w1[r];
            }
    }
    __syncthreads();   // phase-1 staging long done; order before UredF overlay
    #pragma unroll
    for (int i = 0; i < 4; ++i) {
        float a = p0[i], b = p1[i];
        a += __shfl_xor(a, 16, 64);  b += __shfl_xor(b, 16, 64);
        a += __shfl_xor(a, 32, 64);  b += __shfl_xor(b, 32, 64);
        if (hi == 0) {
            UredF[(wc * BM + i * 16 + rl) * 2]     = a;
            UredF[(wc * BM + i * 16 + rl) * 2 + 1] = b;
        }
    }
    __syncthreads();
    if (tid < BM * 2) {
        const int row = tid >> 1, c = tid & 1;
        float s = 0.f;
        #pragma unroll
        for (int q = 0; q < 8; ++q) s += UredF[(q * BM + row) * 2 + c];
        U[(size_t)(tile * BM + row) * 2 + c] = s;
    }
}

// ---- GCN on 2-wide features, dinv scaling applied inline on raw w ----
// out[b,n,c] = dinv[n] * sum_m (w[n,m] + (m==n)) * dinv[m] * U[b*512+m, c] + bc[c]
__global__ void gcn_kernel(const void* __restrict__ w, const float* __restrict__ dinv,
                           const float* __restrict__ U, const float* __restrict__ bcf,
                           const int* __restrict__ flagp, void* __restrict__ out) {
    const int isbf = *flagp;                  // wave-uniform scalar load
    const int wave = threadIdx.x >> 6, lane = threadIdx.x & 63;
    const int task = blockIdx.x * 4 + wave;   // (b, n)
    const int b = task >> 9, n = task & 511;
    const float* ub = U + b * 1024;
    float a0 = 0.f, a1 = 0.f;
    for (int m = lane; m < 512; m += 64) {
        float wv = ldsel(w, n * 512 + m, isbf) + (m == n ? 1.0f : 0.0f);
        const float t = wv * dinv[m];
        a0 += t * ub[m * 2];
        a1 += t * ub[m * 2 + 1];
    }
    #pragma unroll
    for (int off = 32; off; off >>= 1) {
        a0 += __shfl_down(a0, off, 64);
        a1 += __shfl_down(a1, off, 64);
    }
    if (lane == 0) {
        const float dn = dinv[n];
        const float r0 = a0 * dn + bcf[0];
        const float r1 = a1 * dn + bcf[1];
        if (isbf) {
            ((bf16_t*)out)[task * 2]     = __float2bfloat16(r0);
            ((bf16_t*)out)[task * 2 + 1] = __float2bfloat16(r1);
        } else {
            ((float*)out)[task * 2]     = r0;
            ((float*)out)[task * 2 + 1] = r1;
        }
    }
}

extern "C" void kernel_launch(void* const* d_in, const int* in_sizes, int n_in,
                              void* d_out, int out_size, void* d_ws, size_t ws_size,
                              hipStream_t stream) {
    const void* d   = d_in[0];
    const void* w   = d_in[1];
    const void* W1  = d_in[2];
    const void* b1  = d_in[3];
    const void* g1  = d_in[4];
    const void* be1 = d_in[5];
    const void* m1  = d_in[6];
    const void* v1  = d_in[7];
    const void* W2  = d_in[8];
    const void* b2  = d_in[9];
    const void* g2  = d_in[10];
    const void* be2 = d_in[11];
    const void* m2  = d_in[12];
    const void* v2  = d_in[13];
    const void* Wc  = d_in[14];
    const void* bc  = d_in[15];

    // workspace layout: ~1.6 MB total
    char* ws = (char*)d_ws;
    bf16_t* W1pk = (bf16_t*)ws;                        // 512 KB (fragment-major)
    bf16_t* W2pk = (bf16_t*)(ws + 0x080000);           // 512 KB
    float*  sc1  = (float*)(ws + 0x100000);
    float*  sh1  = sc1 + 512;
    float*  sc2  = sh1 + 512;
    float*  sh2  = sc2 + 512;
    float*  dinv = sh2 + 512;
    float*  wcf  = (float*)(ws + 0x104000);            // 4 KB
    float*  bcf  = (float*)(ws + 0x105000);
    int*    flag = (int*)(ws + 0x105100);
    float*  U    = (float*)(ws + 0x108000);            // 512 KB

    const int M = 128 * 512;   // 65536 rows

    prep_kernel<<<257, 256, 0, stream>>>(d, w, W1, W2, g1, b1, m1, v1, be1,
                                         g2, b2, m2, v2, be2, Wc, bc,
                                         dinv, W1pk, W2pk, sc1, sh1, sc2, sh2,
                                         wcf, bcf, flag);

    fused_mlp<<<M / BM, 512, 0, stream>>>(d, W1pk, W2pk,
                                          sc1, sh1, sc2, sh2, wcf, flag, U);

    gcn_kernel<<<M / 4, 256, 0, stream>>>(w, dinv, U, bcf, flag, d_out);
}